// Round 1
// baseline (421.388 us; speedup 1.0000x reference)
//
#include <hip/hip_runtime.h>

#define KSIZE 7
#define SR    2
#define SAMP  (KSIZE * SR)   // 14 sample coords per axis
#define NBINS (KSIZE * KSIZE)

__global__ __launch_bounds__(256) void roialign_kernel(
    const float* __restrict__ x,        // [B,H,W,C]
    const float* __restrict__ rois,     // [N,4] (y1,x1,y2,x2)
    const int*   __restrict__ batch_idx,// [N]
    float*       __restrict__ out,      // [N,K,K,C]
    int N, int H, int W, int C)
{
    const int n = blockIdx.x;
    const int t = threadIdx.x;

    __shared__ int   y0s[SAMP];
    __shared__ float lys[SAMP];
    __shared__ int   x0s[SAMP];
    __shared__ float lxs[SAMP];

    const float y1 = rois[n * 4 + 0];
    const float x1 = rois[n * 4 + 1];
    const float y2 = rois[n * 4 + 2];
    const float x2 = rois[n * 4 + 3];
    const float bin_h = (y2 - y1) / (float)KSIZE;
    const float bin_w = (x2 - x1) / (float)KSIZE;

    if (t < SAMP) {
        const float off = ((float)t + 0.5f) / (float)SR;
        const float sy  = y1 + off * bin_h;
        float fy = floorf(sy);
        fy = fminf(fmaxf(fy, 0.0f), (float)(H - 2));
        y0s[t] = (int)fy;
        lys[t] = fminf(fmaxf(sy - fy, 0.0f), 1.0f);
    } else if (t < 2 * SAMP) {
        const int s = t - SAMP;
        const float off = ((float)s + 0.5f) / (float)SR;
        const float sx  = x1 + off * bin_w;
        float fx = floorf(sx);
        fx = fminf(fmaxf(fx, 0.0f), (float)(W - 2));
        x0s[s] = (int)fx;
        lxs[s] = fminf(fmaxf(sx - fx, 0.0f), 1.0f);
    }
    __syncthreads();

    const int b    = batch_idx[n];
    const int lane = t & 63;        // channel group: lane*4 .. lane*4+3
    const int wave = t >> 6;        // 4 waves per block
    const int C4   = C >> 2;        // channels in float4 units (64)

    const float4* __restrict__ xb =
        (const float4*)(x + (size_t)b * H * W * C);

    for (int bin = wave; bin < NBINS; bin += 4) {
        const int ky = bin / KSIZE;
        const int kx = bin - ky * KSIZE;

        float4 acc = make_float4(0.f, 0.f, 0.f, 0.f);

        #pragma unroll
        for (int i = 0; i < SR; ++i) {
            const int   syi = ky * SR + i;
            const int   y0  = y0s[syi];
            const float ly  = lys[syi];
            #pragma unroll
            for (int j = 0; j < SR; ++j) {
                const int   sxi = kx * SR + j;
                const int   x0  = x0s[sxi];
                const float lx  = lxs[sxi];

                const float4* p = xb + ((size_t)(y0 * W + x0)) * C4 + lane;
                const float4 v00 = p[0];
                const float4 v01 = p[C4];
                const float4 v10 = p[(size_t)W * C4];
                const float4 v11 = p[(size_t)W * C4 + C4];

                const float w00 = (1.f - ly) * (1.f - lx);
                const float w01 = (1.f - ly) * lx;
                const float w10 = ly * (1.f - lx);
                const float w11 = ly * lx;

                acc.x += v00.x * w00 + v01.x * w01 + v10.x * w10 + v11.x * w11;
                acc.y += v00.y * w00 + v01.y * w01 + v10.y * w10 + v11.y * w11;
                acc.z += v00.z * w00 + v01.z * w01 + v10.z * w10 + v11.z * w11;
                acc.w += v00.w * w00 + v01.w * w01 + v10.w * w10 + v11.w * w11;
            }
        }

        float4 r;
        r.x = acc.x * 0.25f;
        r.y = acc.y * 0.25f;
        r.z = acc.z * 0.25f;
        r.w = acc.w * 0.25f;

        float4* op = (float4*)(out + ((size_t)n * NBINS + bin) * C) + lane;
        *op = r;
    }
}

extern "C" void kernel_launch(void* const* d_in, const int* in_sizes, int n_in,
                              void* d_out, int out_size, void* d_ws, size_t ws_size,
                              hipStream_t stream) {
    const float* x         = (const float*)d_in[0];
    const float* rois      = (const float*)d_in[1];
    const int*   batch_idx = (const int*)d_in[2];
    float*       out       = (float*)d_out;

    const int H = 64, W = 64, C = 256;
    const int N = in_sizes[1] / 4;          // rois is [N,4]

    roialign_kernel<<<N, 256, 0, stream>>>(x, rois, batch_idx, out, N, H, W, C);
}

// Round 2
// 352.640 us; speedup vs baseline: 1.1950x; 1.1950x over previous
//
#include <hip/hip_runtime.h>

#define KSIZE 7
#define SR    2
#define SAMP  (KSIZE * SR)   // 14 sample coords per axis
#define NBINS (KSIZE * KSIZE)

typedef float v4f __attribute__((ext_vector_type(4)));

// ws int layout:
//  [0..7]    cnt per batch
//  [8..15]   scatter cursor per batch
//  [16]      overflow produce count
//  [17]      overflow consume cursor
//  [128 .. 128+N)      primary list (B buckets of `cap` slots)
//  [128+N .. 128+2N)   overflow list
#define WS_CNT    0
#define WS_CUR    8
#define WS_OVFC   16
#define WS_OVFT   17
#define WS_PRIM   128

__global__ void count_kernel(const int* __restrict__ bi, int* __restrict__ ws, int N) {
    int i = blockIdx.x * 256 + threadIdx.x;
    if (i < N) atomicAdd(&ws[WS_CNT + bi[i]], 1);
}

__global__ void scatter_kernel(const int* __restrict__ bi, int* __restrict__ ws,
                               int N, int cap) {
    int i = blockIdx.x * 256 + threadIdx.x;
    if (i >= N) return;
    int k = bi[i];
    int p = atomicAdd(&ws[WS_CUR + k], 1);
    if (p < cap) {
        ws[WS_PRIM + k * cap + p] = i;
    } else {
        int q = atomicAdd(&ws[WS_OVFC], 1);
        ws[WS_PRIM + N + q] = i;
    }
}

__global__ void roialign_kernel(
    const float* __restrict__ x,        // [B,H,W,C]
    const float* __restrict__ rois,     // [N,4] (y1,x1,y2,x2)
    const int*   __restrict__ batch_idx,// [N]
    float*       __restrict__ out,      // [N,K,K,C]
    int*         __restrict__ ws,
    int N, int B, int cap, int H, int W, int C)
{
    __shared__ int   sh_n;
    __shared__ int   y0s[SAMP];
    __shared__ float lys[SAMP];
    __shared__ int   x0s[SAMP];
    __shared__ float lxs[SAMP];

    const int t  = threadIdx.x;
    const int bb = blockIdx.x;
    const int k  = bb % B;      // XCD-aligned bucket (blocks round-robin XCDs)
    const int m  = bb / B;

    int cnt = ws[WS_CNT + k];
    if (cnt > cap) cnt = cap;
    if (t == 0) {
        if (m < cnt) {
            sh_n = ws[WS_PRIM + k * cap + m];
        } else {
            int q = atomicAdd(&ws[WS_OVFT], 1);
            sh_n = ws[WS_PRIM + N + q];
        }
    }
    __syncthreads();
    const int n = sh_n;

    const float y1 = rois[n * 4 + 0];
    const float x1 = rois[n * 4 + 1];
    const float y2 = rois[n * 4 + 2];
    const float x2 = rois[n * 4 + 3];
    const float bin_h = (y2 - y1) / (float)KSIZE;
    const float bin_w = (x2 - x1) / (float)KSIZE;

    if (t < SAMP) {
        const float off = ((float)t + 0.5f) / (float)SR;
        const float sy  = y1 + off * bin_h;
        float fy = floorf(sy);
        fy = fminf(fmaxf(fy, 0.0f), (float)(H - 2));
        y0s[t] = (int)fy;
        lys[t] = fminf(fmaxf(sy - fy, 0.0f), 1.0f);
    } else if (t < 2 * SAMP) {
        const int s = t - SAMP;
        const float off = ((float)s + 0.5f) / (float)SR;
        const float sx  = x1 + off * bin_w;
        float fx = floorf(sx);
        fx = fminf(fmaxf(fx, 0.0f), (float)(W - 2));
        x0s[s] = (int)fx;
        lxs[s] = fminf(fmaxf(sx - fx, 0.0f), 1.0f);
    }
    __syncthreads();

    const int bimg = batch_idx[n];
    const int lane = t & 63;
    const int wave = t >> 6;
    const int C4   = C >> 2;     // 64
    const int WC4  = W * C4;

    const float4* __restrict__ xb =
        (const float4*)x + (size_t)bimg * H * WC4 + lane;

    for (int bin = wave; bin < NBINS; bin += 4) {
        const int ky = bin / KSIZE;
        const int kx = bin - ky * KSIZE;

        const int   x0a = x0s[kx * SR + 0];
        const float lxa = lxs[kx * SR + 0];
        const int   x0b = x0s[kx * SR + 1];
        const float lxb = lxs[kx * SR + 1];

        float4 acc = make_float4(0.f, 0.f, 0.f, 0.f);

        #pragma unroll
        for (int i = 0; i < SR; ++i) {
            const int   y0 = y0s[ky * SR + i];
            const float ly = lys[ky * SR + i];

            const float4* pr = xb + y0 * WC4;
            const float4* pa = pr + x0a * C4;
            const float4* pb = pr + x0b * C4;

            // 8 independent 1KB wave-loads in flight per row
            const float4 a00 = pa[0];
            const float4 a01 = pa[C4];
            const float4 a10 = pa[WC4];
            const float4 a11 = pa[WC4 + C4];
            const float4 b00 = pb[0];
            const float4 b01 = pb[C4];
            const float4 b10 = pb[WC4];
            const float4 b11 = pb[WC4 + C4];

            const float wa00 = (1.f - ly) * (1.f - lxa);
            const float wa01 = (1.f - ly) * lxa;
            const float wa10 = ly * (1.f - lxa);
            const float wa11 = ly * lxa;
            const float wb00 = (1.f - ly) * (1.f - lxb);
            const float wb01 = (1.f - ly) * lxb;
            const float wb10 = ly * (1.f - lxb);
            const float wb11 = ly * lxb;

            acc.x += a00.x*wa00 + a01.x*wa01 + a10.x*wa10 + a11.x*wa11
                   + b00.x*wb00 + b01.x*wb01 + b10.x*wb10 + b11.x*wb11;
            acc.y += a00.y*wa00 + a01.y*wa01 + a10.y*wa10 + a11.y*wa11
                   + b00.y*wb00 + b01.y*wb01 + b10.y*wb10 + b11.y*wb11;
            acc.z += a00.z*wa00 + a01.z*wa01 + a10.z*wa10 + a11.z*wa11
                   + b00.z*wb00 + b01.z*wb01 + b10.z*wb10 + b11.z*wb11;
            acc.w += a00.w*wa00 + a01.w*wa01 + a10.w*wa10 + a11.w*wa11
                   + b00.w*wb00 + b01.w*wb01 + b10.w*wb10 + b11.w*wb11;
        }

        v4f r;
        r.x = acc.x * 0.25f;
        r.y = acc.y * 0.25f;
        r.z = acc.z * 0.25f;
        r.w = acc.w * 0.25f;

        v4f* op = (v4f*)(out + ((size_t)n * NBINS + bin) * C) + lane;
        __builtin_nontemporal_store(r, op);   // write-once stream: keep out of L2
    }
}

extern "C" void kernel_launch(void* const* d_in, const int* in_sizes, int n_in,
                              void* d_out, int out_size, void* d_ws, size_t ws_size,
                              hipStream_t stream) {
    const float* x         = (const float*)d_in[0];
    const float* rois      = (const float*)d_in[1];
    const int*   batch_idx = (const int*)d_in[2];
    float*       out       = (float*)d_out;
    int*         ws        = (int*)d_ws;

    const int H = 64, W = 64, C = 256;
    const int N = in_sizes[1] / 4;                 // rois is [N,4]
    const int B = in_sizes[0] / (H * W * C);       // 8
    const int cap = N / B;                         // 512

    hipMemsetAsync(d_ws, 0, 512, stream);          // zero counters
    count_kernel<<<(N + 255) / 256, 256, 0, stream>>>(batch_idx, ws, N);
    scatter_kernel<<<(N + 255) / 256, 256, 0, stream>>>(batch_idx, ws, N, cap);
    roialign_kernel<<<N, 256, 0, stream>>>(x, rois, batch_idx, out, ws,
                                           N, B, cap, H, W, C);
}

// Round 3
// 325.054 us; speedup vs baseline: 1.2964x; 1.0849x over previous
//
#include <hip/hip_runtime.h>

#define KSIZE 7
#define SR    2
#define SAMP  (KSIZE * SR)   // 14 sample coords per axis
#define NBINS (KSIZE * KSIZE)
#define NMAX  4096
#define BMAX  8

typedef float v4f __attribute__((ext_vector_type(4)));

// ---------------------------------------------------------------------------
// One-block bucketing: builds assign[bb] = roi index, such that bb % B ==
// batch of that roi wherever possible (blocks round-robin across the 8 XCDs,
// so bucket k lands on XCD k -> per-XCD L2 holds exactly one image).
// All coordination in LDS; zero global atomics.
// ---------------------------------------------------------------------------
__global__ __launch_bounds__(256) void bucket_kernel(
    const int* __restrict__ bi, int* __restrict__ assign, int N, int B, int cap)
{
    __shared__ int cnt[BMAX];
    __shared__ int ovf_n, ovf_c;
    __shared__ int asg[NMAX];
    __shared__ int ovf[NMAX];

    const int t = threadIdx.x;
    if (t < BMAX) cnt[t] = 0;
    if (t == 0) { ovf_n = 0; ovf_c = 0; }
    for (int i = t; i < N; i += 256) asg[i] = -1;
    __syncthreads();

    for (int i = t; i < N; i += 256) {
        int k = bi[i];
        int p = atomicAdd(&cnt[k], 1);           // LDS atomic: cheap
        if (p < cap) asg[p * B + k] = i;         // primary slot on XCD k
        else { int q = atomicAdd(&ovf_n, 1); ovf[q] = i; }
    }
    __syncthreads();

    for (int i = t; i < N; i += 256) {           // fill holes from overflow
        if (asg[i] < 0) { int q = atomicAdd(&ovf_c, 1); asg[i] = ovf[q]; }
    }
    __syncthreads();

    for (int i = t; i < N; i += 256) assign[i] = asg[i];
}

// ---------------------------------------------------------------------------
// Main kernel: one block per ROI; wave w handles bins w, w+4, ...
// lane = channel group (64 lanes x float4 = 256 channels, fully coalesced).
// launch_bounds(256,4): allow up to 128 VGPR so all 16 loads/bin stay in
// flight (R1's VGPR=32 build serialized them into groups of ~4).
// ---------------------------------------------------------------------------
__global__ __launch_bounds__(256, 4) void roialign_kernel(
    const float* __restrict__ x,         // [B,H,W,C]
    const float* __restrict__ rois,      // [N,4] (y1,x1,y2,x2)
    const int*   __restrict__ batch_idx, // [N]
    float*       __restrict__ out,       // [N,K,K,C]
    const int*   __restrict__ assign,
    int H, int W, int C)
{
    __shared__ int   sh_n;
    __shared__ int   y0s[SAMP];
    __shared__ float lys[SAMP];
    __shared__ int   x0s[SAMP];
    __shared__ float lxs[SAMP];

    const int t = threadIdx.x;
    if (t == 0) sh_n = assign[blockIdx.x];
    __syncthreads();
    const int n = sh_n;

    const float4 rb = ((const float4*)rois)[n];   // (y1,x1,y2,x2) broadcast
    const float bin_h = (rb.z - rb.x) / (float)KSIZE;
    const float bin_w = (rb.w - rb.y) / (float)KSIZE;

    if (t < SAMP) {
        const float off = ((float)t + 0.5f) / (float)SR;
        const float sy  = rb.x + off * bin_h;
        float fy = floorf(sy);
        fy = fminf(fmaxf(fy, 0.0f), (float)(H - 2));
        y0s[t] = (int)fy;
        lys[t] = fminf(fmaxf(sy - fy, 0.0f), 1.0f);
    } else if (t < 2 * SAMP) {
        const int s = t - SAMP;
        const float off = ((float)s + 0.5f) / (float)SR;
        const float sx  = rb.y + off * bin_w;
        float fx = floorf(sx);
        fx = fminf(fmaxf(fx, 0.0f), (float)(W - 2));
        x0s[s] = (int)fx;
        lxs[s] = fminf(fmaxf(sx - fx, 0.0f), 1.0f);
    }
    __syncthreads();

    const int bimg = batch_idx[n];
    const int lane = t & 63;
    const int wave = t >> 6;
    const int C4   = C >> 2;     // 64
    const int WC4  = W * C4;     // 4096

    const v4f* __restrict__ xb =
        (const v4f*)x + (size_t)bimg * H * WC4 + lane;
    float* __restrict__ outn = out + (size_t)n * NBINS * C;

    for (int bin = wave; bin < NBINS; bin += 4) {
        const int ky = bin / KSIZE;
        const int kx = bin - ky * KSIZE;

        // ---- phase 1: addresses + all 16 loads (keep them ALL in flight) --
        const v4f* p[4];
        #pragma unroll
        for (int i = 0; i < SR; ++i) {
            const int y0 = y0s[ky * SR + i];
            #pragma unroll
            for (int j = 0; j < SR; ++j) {
                const int x0 = x0s[kx * SR + j];
                p[i * SR + j] = xb + y0 * WC4 + x0 * C4;
            }
        }

        v4f v[4][4];
        #pragma unroll
        for (int s = 0; s < 4; ++s) {
            v[s][0] = p[s][0];          // (y0  , x0  )
            v[s][1] = p[s][C4];         // (y0  , x0+1)
            v[s][2] = p[s][WC4];        // (y0+1, x0  )
            v[s][3] = p[s][WC4 + C4];   // (y0+1, x0+1)
        }

        // ---- phase 2: weights + FMA ---------------------------------------
        v4f acc = {0.f, 0.f, 0.f, 0.f};
        #pragma unroll
        for (int s = 0; s < 4; ++s) {
            const float ly = lys[ky * SR + (s >> 1)];
            const float lx = lxs[kx * SR + (s & 1)];
            const float w00 = (1.f - ly) * (1.f - lx);
            const float w01 = (1.f - ly) * lx;
            const float w10 = ly * (1.f - lx);
            const float w11 = ly * lx;
            acc += v[s][0] * w00 + v[s][1] * w01 + v[s][2] * w10 + v[s][3] * w11;
        }
        acc *= 0.25f;

        v4f* op = (v4f*)(outn + (size_t)bin * C) + lane;
        __builtin_nontemporal_store(acc, op);    // write-once stream
    }
}

extern "C" void kernel_launch(void* const* d_in, const int* in_sizes, int n_in,
                              void* d_out, int out_size, void* d_ws, size_t ws_size,
                              hipStream_t stream) {
    const float* x         = (const float*)d_in[0];
    const float* rois      = (const float*)d_in[1];
    const int*   batch_idx = (const int*)d_in[2];
    float*       out       = (float*)d_out;
    int*         assign    = (int*)d_ws;

    const int H = 64, W = 64, C = 256;
    const int N = in_sizes[1] / 4;                 // rois is [N,4]
    const int B = in_sizes[0] / (H * W * C);       // 8
    const int cap = N / B;                         // 512

    bucket_kernel<<<1, 256, 0, stream>>>(batch_idx, assign, N, B, cap);
    roialign_kernel<<<N, 256, 0, stream>>>(x, rois, batch_idx, out, assign,
                                           H, W, C);
}